// Round 10
// baseline (189.250 us; speedup 1.0000x reference)
//
#include <hip/hip_runtime.h>
#include <hip/hip_bf16.h>

#define SEQ   512
#define BATCH 1024
#define HD    64
#define NS    4      // samples per block -> 256 blocks (1 block/CU, 4 waves)
#define TCH   64     // chunk: x staged in, h-out staged out, per 64 steps
#define XPAD  80     // padded row length (shorts); de-conflicts slot reads

typedef __attribute__((ext_vector_type(8))) short bf16x8;   // 8 bf16 = 4 VGPR
typedef __attribute__((ext_vector_type(4))) float f32x4;    // MFMA acc

// float -> bf16 raw bits, round-to-nearest-even
__device__ __forceinline__ unsigned short f2bf(float f) {
    unsigned u = __float_as_uint(f);
    return (unsigned short)((u + 0x7FFFu + ((u >> 16) & 1u)) >> 16);
}
// raw v_rcp_f32 (~1 ulp): avoids IEEE div expansion (proven win in v7)
__device__ __forceinline__ float frcp(float x) { return __builtin_amdgcn_rcpf(x); }
__device__ __forceinline__ float fsig(float x) { return frcp(1.f + __expf(-x)); }
__device__ __forceinline__ float ftanh(float x) { return 1.f - 2.f * frcp(__expf(2.f * x) + 1.f); }

// Persistent LSTM, 4 samples/block, 256 blocks (1/CU).
// Wave w owns hidden units [16w,16w+16); N-tiles {w,4+w,8+w,12+w} = i/f/g/o.
// Samples at A-rows {0,4,8,12} (slot=(ln>>2)&3) -> D rows 4q land on reg 0:
// cell update on ALL 64 lanes (sample q=ln>>4, unit w*16+(ln&15)), no
// cross-lane ops. v7 (this round): ZERO global-memory ops inside the step
// loop -- h outputs stage in LDS (ost, fp32) and dump once per chunk, so the
// per-step __syncthreads drains only LDS, not a ~400-cyc store ack (the
// compiler's vmcnt(0)-before-s_barrier). At 1 block/CU nothing else hides
// that drain; this was the hidden serial cost in v3..v6.
__global__ __launch_bounds__(256, 1)
void lstm_v7(const float* __restrict__ x,
             const float* __restrict__ W_ih,
             const float* __restrict__ W_hh,
             const float* __restrict__ b_ih,
             const float* __restrict__ b_hh,
             float* __restrict__ out)
{
    __shared__ __align__(16) unsigned short xch[TCH][NS][XPAD]; // 40 KB bf16
    __shared__ __align__(16) float          ost[TCH][NS][HD];   // 64 KB fp32 h-out
    __shared__ __align__(16) unsigned short hb[2][NS][XPAD];    // 1.25 KB ping-pong

    const int tid  = threadIdx.x;
    const int w    = tid >> 6;        // wave 0..3
    const int ln   = tid & 63;
    const int col  = ln & 15;         // MFMA column / unit within wave
    const int kg   = ln >> 4;         // k-group of A/B fragments
    const int slot = (ln >> 2) & 3;   // A-row (ln&15) -> sample slot (row>>2)
    const int q    = ln >> 4;         // cell-phase sample index
    const int unit = w * 16 + col;
    const int sBase = blockIdx.x * NS;

    // ---- one-time: B fragments global fp32 -> bf16 registers ----
    bf16x8 bfr[4][4];                 // [gate][k-tile]
    #pragma unroll
    for (int g4 = 0; g4 < 4; ++g4) {
        #pragma unroll
        for (int kt = 0; kt < 4; ++kt) {
            const int n = (g4 * 4 + w) * 16 + col;
            const int k = kt * 32 + kg * 8;
            const float* src = (k < 64) ? (W_ih + n * 64 + k)
                                        : (W_hh + n * 64 + (k - 64));
            const float4 lo = *(const float4*)src;
            const float4 hi = *(const float4*)(src + 4);
            bf16x8 v;
            v[0] = (short)f2bf(lo.x); v[1] = (short)f2bf(lo.y);
            v[2] = (short)f2bf(lo.z); v[3] = (short)f2bf(lo.w);
            v[4] = (short)f2bf(hi.x); v[5] = (short)f2bf(hi.y);
            v[6] = (short)f2bf(hi.z); v[7] = (short)f2bf(hi.w);
            bfr[g4][kt] = v;
        }
    }
    // per-lane scalar biases (added on reg0 only, in the cell)
    float bs[4];
    #pragma unroll
    for (int g4 = 0; g4 < 4; ++g4)
        bs[g4] = b_ih[g4 * 64 + unit] + b_hh[g4 * 64 + unit];

    // zero both h buffers (2*NS*XPAD shorts = 320 uints)
    for (int i = tid; i < (2 * NS * XPAD) / 2; i += 256) ((unsigned*)hb)[i] = 0;

    float c_st = 0.f;
    int p = 0;
    const f32x4 z4 = {0.f, 0.f, 0.f, 0.f};

    for (int t0 = 0; t0 < SEQ; t0 += TCH) {
        // ======== inter-chunk region: all global traffic lives here ========
        if (t0 > 0) {
            const int tp = t0 - TCH;
            #pragma unroll
            for (int j = 0; j < (TCH * NS * HD) / (4 * 256); ++j) {   // 16 iters
                const int idx = tid + j * 256;          // f32x4 index
                const int tt  = idx >> 6;               // 64 x4 per step
                const int rem = idx & 63;
                const int sl  = rem >> 4, k4 = rem & 15;
                const f32x4 v = *(const f32x4*)&ost[tt][sl][k4 * 4];
                *(f32x4*)&out[(((size_t)(tp + tt) * BATCH) + sBase + sl) * HD + k4 * 4] = v;
            }
        }
        // refill x chunk: float4 loads, bf16 pack (16 iters/thread)
        #pragma unroll
        for (int j = 0; j < (TCH * NS * 16) / 256; ++j) {
            const int idx = tid + j * 256;      // float4 index
            const int k4 = idx & 15, sl = (idx >> 4) & 3, tt = idx >> 6;
            const float4 v = *(const float4*)&x[(((size_t)(t0 + tt) * BATCH) + sBase + sl) * HD + k4 * 4];
            uint2 pk;
            pk.x = (unsigned)f2bf(v.x) | ((unsigned)f2bf(v.y) << 16);
            pk.y = (unsigned)f2bf(v.z) | ((unsigned)f2bf(v.w) << 16);
            *(uint2*)&xch[tt][sl][k4 * 4] = pk;
        }
        __syncthreads();

        bf16x8 ax0 = *(const bf16x8*)&xch[0][slot][kg * 8];
        bf16x8 ax1 = *(const bf16x8*)&xch[0][slot][32 + kg * 8];

        // ======== 64 steps: LDS-only barrier regions ========
        for (int tc = 0; tc < TCH; ++tc) {
            // h fragments (the only post-barrier latency on the chain)
            const bf16x8 ah0 = *(const bf16x8*)&hb[p][slot][kg * 8];
            const bf16x8 ah1 = *(const bf16x8*)&hb[p][slot][32 + kg * 8];

            // x-part: 4 chains, 2-deep, independent of h (hides ah latency)
            f32x4 xa0 = __builtin_amdgcn_mfma_f32_16x16x32_bf16(ax0, bfr[0][0], z4, 0, 0, 0);
            f32x4 xa1 = __builtin_amdgcn_mfma_f32_16x16x32_bf16(ax0, bfr[1][0], z4, 0, 0, 0);
            f32x4 xa2 = __builtin_amdgcn_mfma_f32_16x16x32_bf16(ax0, bfr[2][0], z4, 0, 0, 0);
            f32x4 xa3 = __builtin_amdgcn_mfma_f32_16x16x32_bf16(ax0, bfr[3][0], z4, 0, 0, 0);
            xa0 = __builtin_amdgcn_mfma_f32_16x16x32_bf16(ax1, bfr[0][1], xa0, 0, 0, 0);
            xa1 = __builtin_amdgcn_mfma_f32_16x16x32_bf16(ax1, bfr[1][1], xa1, 0, 0, 0);
            xa2 = __builtin_amdgcn_mfma_f32_16x16x32_bf16(ax1, bfr[2][1], xa2, 0, 0, 0);
            xa3 = __builtin_amdgcn_mfma_f32_16x16x32_bf16(ax1, bfr[3][1], xa3, 0, 0, 0);
            // h-part: 4 chains, 2-deep
            f32x4 ha0 = __builtin_amdgcn_mfma_f32_16x16x32_bf16(ah0, bfr[0][2], z4, 0, 0, 0);
            f32x4 ha1 = __builtin_amdgcn_mfma_f32_16x16x32_bf16(ah0, bfr[1][2], z4, 0, 0, 0);
            f32x4 ha2 = __builtin_amdgcn_mfma_f32_16x16x32_bf16(ah0, bfr[2][2], z4, 0, 0, 0);
            f32x4 ha3 = __builtin_amdgcn_mfma_f32_16x16x32_bf16(ah0, bfr[3][2], z4, 0, 0, 0);
            ha0 = __builtin_amdgcn_mfma_f32_16x16x32_bf16(ah1, bfr[0][3], ha0, 0, 0, 0);
            ha1 = __builtin_amdgcn_mfma_f32_16x16x32_bf16(ah1, bfr[1][3], ha1, 0, 0, 0);
            ha2 = __builtin_amdgcn_mfma_f32_16x16x32_bf16(ah1, bfr[2][3], ha2, 0, 0, 0);
            ha3 = __builtin_amdgcn_mfma_f32_16x16x32_bf16(ah1, bfr[3][3], ha3, 0, 0, 0);

            // prefetch next step's x fragments (chunk-stable; hides ds latency)
            bf16x8 nx0 = ax0, nx1 = ax1;
            if (tc + 1 < TCH) {
                nx0 = *(const bf16x8*)&xch[tc + 1][slot][kg * 8];
                nx1 = *(const bf16x8*)&xch[tc + 1][slot][32 + kg * 8];
            }

            // ---- cell update on ALL 64 lanes: sample q, unit w*16+col ----
            const float gi = xa0[0] + ha0[0] + bs[0];
            const float gf = xa1[0] + ha1[0] + bs[1];
            const float gg = xa2[0] + ha2[0] + bs[2];
            const float go = xa3[0] + ha3[0] + bs[3];
            const float iv = fsig(gi);
            const float fv = fsig(gf);
            const float gv = ftanh(gg);
            const float ov = fsig(go);
            c_st = fv * c_st + iv * gv;
            const float h  = ov * ftanh(c_st);
            ost[tc][q][unit]   = h;          // LDS staging (no global store!)
            hb[p ^ 1][q][unit] = f2bf(h);

            ax0 = nx0; ax1 = nx1;
            p ^= 1;
            __syncthreads();   // LDS-only drain: h(t) visible for t+1
        }
    }

    // ---- final chunk dump ----
    {
        const int tp = SEQ - TCH;
        #pragma unroll
        for (int j = 0; j < (TCH * NS * HD) / (4 * 256); ++j) {
            const int idx = tid + j * 256;
            const int tt  = idx >> 6;
            const int rem = idx & 63;
            const int sl  = rem >> 4, k4 = rem & 15;
            const f32x4 v = *(const f32x4*)&ost[tt][sl][k4 * 4];
            *(f32x4*)&out[(((size_t)(tp + tt) * BATCH) + sBase + sl) * HD + k4 * 4] = v;
        }
    }
}

extern "C" void kernel_launch(void* const* d_in, const int* in_sizes, int n_in,
                              void* d_out, int out_size, void* d_ws, size_t ws_size,
                              hipStream_t stream) {
    const float* x    = (const float*)d_in[0];
    const float* W_ih = (const float*)d_in[1];
    const float* W_hh = (const float*)d_in[2];
    const float* b_ih = (const float*)d_in[3];
    const float* b_hh = (const float*)d_in[4];
    float* out = (float*)d_out;

    lstm_v7<<<BATCH / NS, 256, 0, stream>>>(x, W_ih, W_hh, b_ih, b_hh, out);
}

// Round 11
// 186.222 us; speedup vs baseline: 1.0163x; 1.0163x over previous
//
#include <hip/hip_runtime.h>
#include <hip/hip_bf16.h>

#define SEQ   512
#define BATCH 1024
#define HD    64
#define NS    4      // samples per block -> 256 blocks (1 block/CU, 8 waves)
#define TCH   64     // x-chunk steps per LDS buffer
#define XPAD  80     // padded row length (shorts)

typedef __attribute__((ext_vector_type(8))) short bf16x8;   // 8 bf16 = 4 VGPR
typedef __attribute__((ext_vector_type(4))) float f32x4;    // MFMA acc

// float -> bf16 raw bits, round-to-nearest-even
__device__ __forceinline__ unsigned short f2bf(float f) {
    unsigned u = __float_as_uint(f);
    return (unsigned short)((u + 0x7FFFu + ((u >> 16) & 1u)) >> 16);
}
// raw v_rcp_f32 (~1 ulp): avoids IEEE div expansion (proven win, v7 round)
__device__ __forceinline__ float frcp(float x) { return __builtin_amdgcn_rcpf(x); }
__device__ __forceinline__ float fsig(float x) { return frcp(1.f + __expf(-x)); }
__device__ __forceinline__ float ftanh(float x) { return 1.f - 2.f * frcp(__expf(2.f * x) + 1.f); }

// Producer/consumer persistent LSTM. 8 waves, 4 samples, 256 blocks (1/CU).
// h-waves (0-3): pure-LDS recurrence -- ds_read h + 8 MFMA (W_hh, K=64) +
//   cell + LDS h-write. NO VMEM ops ever (no vmcnt drain at the barrier).
// x-waves (4-7): produce xg(t+1) = W_ih.x(t+1) + bias into a 2-slot LDS ring
//   (8 MFMA, K=64), stage x chunks (double-buffered), store out(t-1) from an
//   fp32 LDS h-mirror. All global traffic + latency lives in their slack.
// Same SIMD hosts one h-wave + one x-wave -> x work fills h-wave stalls.
// One barrier/step serves h-exchange and ring handoff.
// Sample q sits at A/D row 4q: D reg0 of lane group q = (sample q, unit
// u*16+(ln&15)) -- cell on all 64 lanes, no cross-lane ops (v6-verified).
__global__ __launch_bounds__(512, 1)
void lstm_v8(const float* __restrict__ x,
             const float* __restrict__ W_ih,
             const float* __restrict__ W_hh,
             const float* __restrict__ b_ih,
             const float* __restrict__ b_hh,
             float* __restrict__ out)
{
    __shared__ __align__(16) unsigned short xch[2][TCH][NS][XPAD]; // 80 KB bf16
    __shared__ __align__(16) float          xg[2][NS][HD][4];      // 8 KB ring
    __shared__ __align__(16) unsigned short hb[2][NS][XPAD];       // bf16 h
    __shared__ __align__(16) float          hf[2][NS][HD + 4];     // fp32 h

    const int tid  = threadIdx.x;
    const int w    = tid >> 6;          // wave 0..7
    const int ln   = tid & 63;
    const int col  = ln & 15;
    const int kg   = ln >> 4;           // k-group of A/B fragments
    const int slot = (ln >> 2) & 3;     // A-row -> sample slot (row>>2)
    const int q    = ln >> 4;           // D reg0 -> sample index
    const int sBase = blockIdx.x * NS;
    const bool isH = (w < 4);
    const int u    = isH ? w : (w - 4); // tile-set index (units [16u,16u+16))
    const int unit = u * 16 + col;

    // ---- one-time: 8 B-fragments (this role's weight half, K=64) ----
    const float* Wsrc = isH ? W_hh : W_ih;
    bf16x8 bfr[4][2];                   // [gate][k-subtile]
    #pragma unroll
    for (int g4 = 0; g4 < 4; ++g4) {
        #pragma unroll
        for (int kt = 0; kt < 2; ++kt) {
            const int n = (g4 * 4 + u) * 16 + col;
            const int k = kt * 32 + kg * 8;
            const float4 lo = *(const float4*)(Wsrc + n * 64 + k);
            const float4 hi = *(const float4*)(Wsrc + n * 64 + k + 4);
            bf16x8 v;
            v[0] = (short)f2bf(lo.x); v[1] = (short)f2bf(lo.y);
            v[2] = (short)f2bf(lo.z); v[3] = (short)f2bf(lo.w);
            v[4] = (short)f2bf(hi.x); v[5] = (short)f2bf(hi.y);
            v[6] = (short)f2bf(hi.z); v[7] = (short)f2bf(hi.w);
            bfr[g4][kt] = v;
        }
    }
    // x-waves: bias in the C operand of the x-projection chains
    f32x4 bias4[4];
    #pragma unroll
    for (int g4 = 0; g4 < 4; ++g4) {
        const float b = isH ? 0.f : (b_ih[g4 * 64 + unit] + b_hh[g4 * 64 + unit]);
        bias4[g4][0] = b; bias4[g4][1] = b; bias4[g4][2] = b; bias4[g4][3] = b;
    }

    // zero h buffers
    for (int i = tid; i < (2 * NS * XPAD) / 2; i += 512) ((unsigned*)hb)[i] = 0;

    const int L = (w - 4) * 64 + ln;    // x-lane id 0..255 (x-waves)
    const int qq = (L >> 6) & 3, uu = L & 63;  // out-store mapping

    // refill chunk C into xch buffer b (x-waves only; 16 float4 per lane)
    auto refill = [&](int C, int b) {
        #pragma unroll
        for (int j = 0; j < 16; ++j) {
            const int idx = L + j * 256;
            const int k4 = idx & 15, sl = (idx >> 4) & 3, tt = idx >> 6;
            const float4 v = *(const float4*)&x[(((size_t)(C * TCH + tt) * BATCH) + sBase + sl) * HD + k4 * 4];
            uint2 pk;
            pk.x = (unsigned)f2bf(v.x) | ((unsigned)f2bf(v.y) << 16);
            pk.y = (unsigned)f2bf(v.z) | ((unsigned)f2bf(v.w) << 16);
            *(uint2*)&xch[b][tt][sl][k4 * 4] = pk;
        }
    };
    // produce xg for step tn (x-waves only): 8 MFMA, bias in C
    auto produce = [&](int tn) {
        const int cb = (tn >> 6) & 1, tc = tn & 63;
        const bf16x8 ax0 = *(const bf16x8*)&xch[cb][tc][slot][kg * 8];
        const bf16x8 ax1 = *(const bf16x8*)&xch[cb][tc][slot][32 + kg * 8];
        f32x4 a0 = __builtin_amdgcn_mfma_f32_16x16x32_bf16(ax0, bfr[0][0], bias4[0], 0, 0, 0);
        f32x4 a1 = __builtin_amdgcn_mfma_f32_16x16x32_bf16(ax0, bfr[1][0], bias4[1], 0, 0, 0);
        f32x4 a2 = __builtin_amdgcn_mfma_f32_16x16x32_bf16(ax0, bfr[2][0], bias4[2], 0, 0, 0);
        f32x4 a3 = __builtin_amdgcn_mfma_f32_16x16x32_bf16(ax0, bfr[3][0], bias4[3], 0, 0, 0);
        a0 = __builtin_amdgcn_mfma_f32_16x16x32_bf16(ax1, bfr[0][1], a0, 0, 0, 0);
        a1 = __builtin_amdgcn_mfma_f32_16x16x32_bf16(ax1, bfr[1][1], a1, 0, 0, 0);
        a2 = __builtin_amdgcn_mfma_f32_16x16x32_bf16(ax1, bfr[2][1], a2, 0, 0, 0);
        a3 = __builtin_amdgcn_mfma_f32_16x16x32_bf16(ax1, bfr[3][1], a3, 0, 0, 0);
        f32x4 v; v[0] = a0[0]; v[1] = a1[0]; v[2] = a2[0]; v[3] = a3[0];
        *(f32x4*)&xg[tn & 1][q][unit][0] = v;
    };

    // ---- prologue: chunk 0 staged; xg[0] produced ----
    if (!isH) refill(0, 0);
    __syncthreads();
    if (!isH) produce(0);
    __syncthreads();

    float c_st = 0.f;
    int p = 0;
    const f32x4 z4 = {0.f, 0.f, 0.f, 0.f};

    for (int t = 0; t < SEQ; ++t) {
        if (isH) {
            // ---- recurrence: LDS + MFMA + VALU only ----
            const bf16x8 ah0 = *(const bf16x8*)&hb[p][slot][kg * 8];
            const bf16x8 ah1 = *(const bf16x8*)&hb[p][slot][32 + kg * 8];
            const f32x4  xgv = *(const f32x4*)&xg[t & 1][q][unit][0];
            __builtin_amdgcn_s_setprio(1);
            f32x4 a0 = __builtin_amdgcn_mfma_f32_16x16x32_bf16(ah0, bfr[0][0], z4, 0, 0, 0);
            f32x4 a1 = __builtin_amdgcn_mfma_f32_16x16x32_bf16(ah0, bfr[1][0], z4, 0, 0, 0);
            f32x4 a2 = __builtin_amdgcn_mfma_f32_16x16x32_bf16(ah0, bfr[2][0], z4, 0, 0, 0);
            f32x4 a3 = __builtin_amdgcn_mfma_f32_16x16x32_bf16(ah0, bfr[3][0], z4, 0, 0, 0);
            a0 = __builtin_amdgcn_mfma_f32_16x16x32_bf16(ah1, bfr[0][1], a0, 0, 0, 0);
            a1 = __builtin_amdgcn_mfma_f32_16x16x32_bf16(ah1, bfr[1][1], a1, 0, 0, 0);
            a2 = __builtin_amdgcn_mfma_f32_16x16x32_bf16(ah1, bfr[2][1], a2, 0, 0, 0);
            a3 = __builtin_amdgcn_mfma_f32_16x16x32_bf16(ah1, bfr[3][1], a3, 0, 0, 0);
            __builtin_amdgcn_s_setprio(0);
            const float iv = fsig(xgv[0] + a0[0]);
            const float fv = fsig(xgv[1] + a1[0]);
            const float gv = ftanh(xgv[2] + a2[0]);
            const float ov = fsig(xgv[3] + a3[0]);
            c_st = fv * c_st + iv * gv;
            const float h = ov * ftanh(c_st);
            hb[p ^ 1][q][unit] = f2bf(h);
            hf[p ^ 1][q][unit] = h;
        } else {
            // ---- producer: staging, x-projection, out-store ----
            if ((t & 63) == 0 && t + TCH < SEQ)
                refill((t >> 6) + 1, ((t >> 6) + 1) & 1);
            if (t + 1 < SEQ) produce(t + 1);
            if (t >= 1)
                out[((size_t)(t - 1) * BATCH + sBase + qq) * HD + uu] = hf[p][qq][uu];
        }
        p ^= 1;
        __syncthreads();
    }
    // final out row: h(SEQ-1) sits in hf[p]
    if (!isH)
        out[((size_t)(SEQ - 1) * BATCH + sBase + qq) * HD + uu] = hf[p][qq][uu];
}

extern "C" void kernel_launch(void* const* d_in, const int* in_sizes, int n_in,
                              void* d_out, int out_size, void* d_ws, size_t ws_size,
                              hipStream_t stream) {
    const float* x    = (const float*)d_in[0];
    const float* W_ih = (const float*)d_in[1];
    const float* W_hh = (const float*)d_in[2];
    const float* b_ih = (const float*)d_in[3];
    const float* b_hh = (const float*)d_in[4];
    float* out = (float*)d_out;

    lstm_v8<<<BATCH / NS, 512, 0, stream>>>(x, W_ih, W_hh, b_ih, b_hh, out);
}